// Round 7
// baseline (241.498 us; speedup 1.0000x reference)
//
#include <hip/hip_runtime.h>
#include <hip/hip_bf16.h>

// MultiHeadAttention fused pipeline. FP32 in/out, bf16 MFMA compute, fp32 accum.
// B=2 T=2048 C=1024 H=16 D=64.
// Stage 0: convert x,W* -> bf16 fragment-major (wave frag load = 1KB burst).
// Stage 1: QKV GEMM zero-LDS streaming; RoPE + exp2 scale fused. Q row-major;
//          K QK-B-frag-major; V PV-B-frag-major natural k (8B short4v stores).
// Stage 2: attention, CAUSAL-PAIRED q-tiles + PARITY-SPLIT 8-wave blocks:
//          block g = (bh, p) handles q-tiles tHi=31-p, tLo=p. Waves 0-3 do
//          even chunks, waves 4-7 odd chunks (disjoint -> K/V loaded once
//          per pair; ~16.5 tile-steps per half, balanced). 512 blocks x 8
//          waves = 4 waves/SIMD (2x r6 TLP). No-max softmax => partial
//          (o,l) are plain sums: cross-half combine is one LDS add pass.
//          No per-step lgkmcnt asm (same-wave DS is FIFO; compiler inserts
//          the precise wait). P per-wave LDS, stride 68 (0 conflicts).
// Stage 3: out GEMM zero-LDS streaming 128x128 block / 64x64 wave.
//
// MFMA layouts (HW-verified): A[m=lane&15][k=quad*8+j]; B[n=lane&15][k=quad*8+j];
// C/D: row=quad*4+reg, col=lane&15.

typedef __hip_bfloat16 bf16;
typedef __attribute__((ext_vector_type(8))) short bf16x8;
typedef __attribute__((ext_vector_type(4))) float f32x4;
typedef __attribute__((ext_vector_type(4))) short short4v;

#define MFMA16(a, b, c) __builtin_amdgcn_mfma_f32_16x16x32_bf16((a), (b), (c), 0, 0, 0)

constexpr int Bn = 2, Hn = 16, Tn = 2048, Dn = 64, Cn = 1024;
constexpr size_t NE = (size_t)Bn * Tn * Cn;   // 4,194,304
constexpr size_t WE = (size_t)Cn * Cn;        // 1,048,576
constexpr float QSCALE = 0.125f * 1.44269504088896f;   // 1/8 * log2(e)
constexpr int PS = 68;   // P-buffer row stride in shorts (2-way banks = free)
constexpr int CS = 66;   // combine-buffer row stride in floats (col 64 = l)

__device__ inline unsigned short bfbits(float x) {
    bf16 b = __float2bfloat16(x);
    return *(unsigned short*)&b;
}

__device__ inline bf16x8 pack8(f32x4 a, f32x4 b) {
    bf16x8 r;
#pragma unroll
    for (int i = 0; i < 4; ++i) r[i] = (short)bfbits(a[i]);
#pragma unroll
    for (int i = 0; i < 4; ++i) r[4 + i] = (short)bfbits(b[i]);
    return r;
}

// ---------------------------------------------------------------- convert
// blocks [0,2048): x -> fragment-major. [2048,4096): W* -> fragment-major.
__global__ __launch_bounds__(256) void convert_kernel(
    const float* __restrict__ x, const float* __restrict__ wq,
    const float* __restrict__ wk, const float* __restrict__ wv,
    const float* __restrict__ wo, bf16* __restrict__ dst)
{
    int blk = blockIdx.x;
    int lane = threadIdx.x & 63;
    int lx = lane & 15, quad = lane >> 4;
    const float* src;
    size_t doff;
    if (blk < 2048) {
        int frag = blk * 4 + (threadIdx.x >> 6);   // 0..8191
        int mt = frag >> 5, kc = frag & 31;
        src = x + (size_t)(mt * 16 + lx) * Cn + kc * 32 + quad * 8;
        doff = (size_t)frag * 512 + lane * 8;
    } else {
        int w = (blk - 2048) >> 9, b = (blk - 2048) & 511;
        const float* s4[4] = {wq, wk, wv, wo};
        int frag = b * 4 + (threadIdx.x >> 6);     // 0..2047
        int nb = frag >> 5, kc = frag & 31;
        src = s4[w] + (size_t)(nb * 16 + lx) * Cn + kc * 32 + quad * 8;
        doff = NE + (size_t)w * WE + (size_t)frag * 512 + lane * 8;
    }
    f32x4 a = *(const f32x4*)(src);
    f32x4 b2 = *(const f32x4*)(src + 4);
    *(bf16x8*)(dst + doff) = pack8(a, b2);
}

// ---------------------------------------------------------------- QKV GEMM
// ZERO-LDS streaming GEMM (round-0 proven): 4 waves (2x2), wave 64x64,
// K-step 32, cur/next prefetch, no barriers. Epilogue: Q row-major;
// K frag-major; V natural-frag (8B short4v stores).
__global__ __launch_bounds__(256) void gemm_qkv_kernel(
    const bf16* __restrict__ Xf, const bf16* __restrict__ Wbase,
    bf16* __restrict__ Qo, bf16* __restrict__ Ko, bf16* __restrict__ Vo)
{
    const int bm = blockIdx.x, bn = blockIdx.y, wsel = blockIdx.z;
    const bf16* W = Wbase + (size_t)wsel * WE;
    const int tid  = threadIdx.x;
    const int wave = tid >> 6, lane = tid & 63;
    const int lx   = lane & 15, quad = lane >> 4;
    const int wm = wave >> 1, wn = wave & 1;

    const int mt0 = bm * 8 + wm * 4;
    const int nb0 = bn * 8 + wn * 4;
    const bf16* afrag = Xf + (size_t)mt0 * 32 * 512 + (size_t)lane * 8;
    const bf16* wfrag = W + (size_t)nb0 * 32 * 512 + (size_t)lane * 8;

    f32x4 acc[4][4] = {};   // [mt][nt]
    bf16x8 acur[4], bcur[4], anxt[4], bnxt[4];
#pragma unroll
    for (int i = 0; i < 4; ++i) {
        acur[i] = *(const bf16x8*)(afrag + (size_t)i * 32 * 512);
        bcur[i] = *(const bf16x8*)(wfrag + (size_t)i * 32 * 512);
    }
    for (int kc = 0; kc < 32; ++kc) {
        if (kc < 31) {
#pragma unroll
            for (int i = 0; i < 4; ++i) {
                anxt[i] = *(const bf16x8*)(afrag + ((size_t)i * 32 + kc + 1) * 512);
                bnxt[i] = *(const bf16x8*)(wfrag + ((size_t)i * 32 + kc + 1) * 512);
            }
        }
#pragma unroll
        for (int mt = 0; mt < 4; ++mt)
#pragma unroll
            for (int nt = 0; nt < 4; ++nt)
                acc[mt][nt] = MFMA16(acur[mt], bcur[nt], acc[mt][nt]);
#pragma unroll
        for (int i = 0; i < 4; ++i) { acur[i] = anxt[i]; bcur[i] = bnxt[i]; }
    }

    const int h = bn * 2 + wn;   // 64-col wave block == one head
    if (wsel <= 1) {             // fused RoPE: pair (d, d+32) = (nt, nt+2)
#pragma unroll
        for (int mt = 0; mt < 4; ++mt)
#pragma unroll
            for (int r = 0; r < 4; ++r) {
                int mg = bm * 128 + wm * 64 + mt * 16 + quad * 4 + r;
                int t  = mg & (Tn - 1);
#pragma unroll
                for (int nt = 0; nt < 2; ++nt) {
                    int d = nt * 16 + lx;   // 0..31
                    float ang = (float)t * __expf(-(float)d * 0.2878231366f);
                    float c, s;
                    __sincosf(ang, &s, &c);
                    float a0 = acc[mt][nt][r], a1 = acc[mt][nt + 2][r];
                    acc[mt][nt][r]     = a0 * c - a1 * s;
                    acc[mt][nt + 2][r] = a1 * c + a0 * s;
                }
            }
    }

#pragma unroll
    for (int mt = 0; mt < 4; ++mt) {
        int mg0 = bm * 128 + wm * 64 + mt * 16 + quad * 4;
        int b = mg0 >> 11, tlo = mg0 & (Tn - 1);
        if (wsel == 0) {        // Q: row-major [B,H,T,D], exp2-folded scale
#pragma unroll
            for (int nt = 0; nt < 4; ++nt)
#pragma unroll
                for (int r = 0; r < 4; ++r) {
                    int d = nt * 16 + lx;
                    Qo[((size_t)(b * Hn + h) * Tn + tlo + r) * Dn + d] =
                        __float2bfloat16(acc[mt][nt][r] * QSCALE);
                }
        } else if (wsel == 1) { // K: QK-B-fragment-major per head
            bf16* Kf = Ko + (size_t)(b * Hn + h) * Tn * Dn;
            int c = tlo >> 6, ntk = (tlo >> 4) & 3;
#pragma unroll
            for (int nt = 0; nt < 4; ++nt) {
                size_t base = ((size_t)(c * 4 + ntk) * 2 + (nt >> 1)) * 512
                            + (size_t)((nt & 1) * 2 + (lx >> 3)) * 128
                            + (size_t)(tlo & 15) * 8 + (lx & 7);
#pragma unroll
                for (int r = 0; r < 4; ++r)
                    Kf[base + (size_t)r * 8] = __float2bfloat16(acc[mt][nt][r]);
            }
        } else {                // V: natural-k frag-major, 8B stores (r13)
            bf16* Vf = Vo + (size_t)(b * Hn + h) * Tn * Dn;
            int c = tlo >> 6, ksv = (tlo >> 5) & 1;
            int qv = (tlo >> 3) & 3, pos0 = tlo & 7;
#pragma unroll
            for (int nt = 0; nt < 4; ++nt) {
                short4v pk;
#pragma unroll
                for (int r = 0; r < 4; ++r) pk[r] = (short)bfbits(acc[mt][nt][r]);
                *(short4v*)&Vf[((size_t)(c * 8 + nt * 2 + ksv)) * 512
                               + (size_t)qv * 128 + (size_t)lx * 8 + pos0] = pk;
            }
        }
    }
}

// ---------------------------------------------------------------- out GEMM
// ZERO-LDS streaming, 128x128 block / 64x64 wave. Grid (32, 8).
__global__ __launch_bounds__(256) void gemm_out_kernel(
    const bf16* __restrict__ Af, const bf16* __restrict__ W, float* __restrict__ Out)
{
    const int bm = blockIdx.x, bn = blockIdx.y;
    const int tid  = threadIdx.x;
    const int wave = tid >> 6, lane = tid & 63;
    const int lx   = lane & 15, quad = lane >> 4;
    const int wm = wave >> 1, wn = wave & 1;

    const int mt0 = bm * 8 + wm * 4;
    const int nb0 = bn * 8 + wn * 4;
    const bf16* afrag = Af + (size_t)mt0 * 32 * 512 + (size_t)lane * 8;
    const bf16* wfrag = W + (size_t)nb0 * 32 * 512 + (size_t)lane * 8;

    f32x4 acc[4][4] = {};
    bf16x8 acur[4], bcur[4], anxt[4], bnxt[4];
#pragma unroll
    for (int i = 0; i < 4; ++i) {
        acur[i] = *(const bf16x8*)(afrag + (size_t)i * 32 * 512);
        bcur[i] = *(const bf16x8*)(wfrag + (size_t)i * 32 * 512);
    }
    for (int kc = 0; kc < 32; ++kc) {
        if (kc < 31) {
#pragma unroll
            for (int i = 0; i < 4; ++i) {
                anxt[i] = *(const bf16x8*)(afrag + ((size_t)i * 32 + kc + 1) * 512);
                bnxt[i] = *(const bf16x8*)(wfrag + ((size_t)i * 32 + kc + 1) * 512);
            }
        }
#pragma unroll
        for (int mt = 0; mt < 4; ++mt)
#pragma unroll
            for (int nt = 0; nt < 4; ++nt)
                acc[mt][nt] = MFMA16(acur[mt], bcur[nt], acc[mt][nt]);
#pragma unroll
        for (int i = 0; i < 4; ++i) { acur[i] = anxt[i]; bcur[i] = bnxt[i]; }
    }
#pragma unroll
    for (int mt = 0; mt < 4; ++mt)
#pragma unroll
        for (int nt = 0; nt < 4; ++nt)
#pragma unroll
            for (int r = 0; r < 4; ++r) {
                int mg = bm * 128 + wm * 64 + mt * 16 + quad * 4 + r;
                int ng = bn * 128 + wn * 64 + nt * 16 + lx;
                Out[(size_t)mg * Cn + ng] = acc[mt][nt][r];
            }
}

// ---------------------------------------------------------------- Attention
// 512 blocks x 512 threads (8 waves). g -> bh = g&31, p = g>>5.
// Waves 0-3 (half 0): even chunks; waves 4-7 (half 1): odd chunks.
// Per chunk: one K/V register load, hi tile-step always, lo tile-step
// while c<=tLo. Partial (o,l) summed across halves via LDS at the end
// (no-max softmax => plain addition). Zero-LDS K/V; P per-wave, stride 68.
__global__ __launch_bounds__(512, 4) void attn_kernel(
    const bf16* __restrict__ Q, const bf16* __restrict__ K,
    const bf16* __restrict__ Vt, bf16* __restrict__ O)
{
    __shared__ unsigned short Pl[8][16 * PS];
    __shared__ float Cb[4][16 * CS];   // combine: [w4][row][ch], col 64 = l
    const int g  = blockIdx.x;
    const int bh = g & 31;
    const int p  = g >> 5;              // 0..15
    const int tHi = 31 - p, tLo = p;    // tHi >= 16 > 15 >= tLo
    const int tid  = threadIdx.x;
    const int wave = tid >> 6, lane = tid & 63;
    const int w4   = wave & 3, half = wave >> 2;
    const int lx   = lane & 15, quad = lane >> 4;

    const bf16* Qh = Q  + (size_t)bh * Tn * Dn;
    const bf16* Kh = K  + (size_t)bh * Tn * Dn;   // frag-major, 4096 shorts/chunk
    const bf16* Vh = Vt + (size_t)bh * Tn * Dn;   // natural-k frag-major
    unsigned short* pw = &Pl[wave][0];
    float* cb = &Cb[w4][0];

    const int qrowH = tHi * 64 + w4 * 16 + lx;    // A-frag m index (hi tile)
    bf16x8 aqH0 = *(const bf16x8*)(Qh + (size_t)qrowH * Dn + quad * 8);
    bf16x8 aqH1 = *(const bf16x8*)(Qh + (size_t)qrowH * Dn + 32 + quad * 8);
    const int qrowL = tLo * 64 + w4 * 16 + lx;    // (lo tile)
    bf16x8 aqL0 = *(const bf16x8*)(Qh + (size_t)qrowL * Dn + quad * 8);
    bf16x8 aqL1 = *(const bf16x8*)(Qh + (size_t)qrowL * Dn + 32 + quad * 8);

    bf16x8 ones;
#pragma unroll
    for (int i = 0; i < 8; ++i) ones[i] = (short)0x3F80;

    f32x4 acc_oH[4] = {}, acc_oL[4] = {};
    f32x4 acc_lH = {},    acc_lL = {};
    const int row_local = w4 * 16 + quad * 4;

    // softmax -> per-wave P buffer (slot = key, natural order)
    auto storeP = [&](const f32x4* accs, bool diag) {
        if (!diag) {
#pragma unroll
            for (int nt = 0; nt < 4; ++nt)
#pragma unroll
                for (int r = 0; r < 4; ++r)
                    pw[(quad * 4 + r) * PS + nt * 16 + lx] = bfbits(exp2f(accs[nt][r]));
        } else {
#pragma unroll
            for (int nt = 0; nt < 4; ++nt) {
                int keyl = nt * 16 + lx;
#pragma unroll
                for (int r = 0; r < 4; ++r) {
                    float pv = (keyl > row_local + r) ? 0.0f : exp2f(accs[nt][r]);
                    pw[(quad * 4 + r) * PS + nt * 16 + lx] = bfbits(pv);
                }
            }
        }
    };

    for (int c = half; c <= tHi; c += 2) {
        // K/V chunk load (registers; L2-resident frag-major layout)
        const bf16* kp = Kh + (size_t)c * 4096 + lane * 8;
        const bf16* vp = Vh + (size_t)c * 4096 + lane * 8;
        bf16x8 k[8], v[8];
#pragma unroll
        for (int i = 0; i < 8; ++i) {
            k[i] = *(const bf16x8*)(kp + (size_t)i * 512);
            v[i] = *(const bf16x8*)(vp + (size_t)i * 512);
        }
        const bool lo = (c <= tLo);
        // QK for both tiles first (independent MFMAs; scheduler freedom)
        f32x4 accsH[4] = {};
#pragma unroll
        for (int nt = 0; nt < 4; ++nt) {
            accsH[nt] = MFMA16(aqH0, k[nt * 2], accsH[nt]);
            accsH[nt] = MFMA16(aqH1, k[nt * 2 + 1], accsH[nt]);
        }
        f32x4 accsL[4] = {};
        if (lo) {
#pragma unroll
            for (int nt = 0; nt < 4; ++nt) {
                accsL[nt] = MFMA16(aqL0, k[nt * 2], accsL[nt]);
                accsL[nt] = MFMA16(aqL1, k[nt * 2 + 1], accsL[nt]);
            }
        }
        // ---- hi tile: softmax -> P -> l,PV (DS FIFO orders write->read;
        // compiler inserts the precise lgkmcnt before the MFMA consumer)
        storeP(accsH, c == tHi);
        {
            bf16x8 ap0 = *(const bf16x8*)&pw[lx * PS + quad * 8];
            bf16x8 ap1 = *(const bf16x8*)&pw[lx * PS + 32 + quad * 8];
            acc_lH = MFMA16(ap0, ones, acc_lH);
            acc_lH = MFMA16(ap1, ones, acc_lH);
#pragma unroll
            for (int dt = 0; dt < 4; ++dt) {
                acc_oH[dt] = MFMA16(ap0, v[dt * 2], acc_oH[dt]);
                acc_oH[dt] = MFMA16(ap1, v[dt * 2 + 1], acc_oH[dt]);
            }
        }
        // ---- lo tile: same P buffer reused (same-wave DS ops are in-order)
        if (lo) {
            storeP(accsL, c == tLo);
            bf16x8 ap0 = *(const bf16x8*)&pw[lx * PS + quad * 8];
            bf16x8 ap1 = *(const bf16x8*)&pw[lx * PS + 32 + quad * 8];
            acc_lL = MFMA16(ap0, ones, acc_lL);
            acc_lL = MFMA16(ap1, ones, acc_lL);
#pragma unroll
            for (int dt = 0; dt < 4; ++dt) {
                acc_oL[dt] = MFMA16(ap0, v[dt * 2], acc_oL[dt]);
                acc_oL[dt] = MFMA16(ap1, v[dt * 2 + 1], acc_oL[dt]);
            }
        }
    }

    // ---- cross-half combine (no-max softmax => partials just add) + write
    const int b = bh >> 4, h = bh & 15;
    auto writeO = [&](int t, const f32x4* acc_o, const f32x4& acc_l) {
        const int mtile = b * 128 + t * 4 + w4;
#pragma unroll
        for (int dt = 0; dt < 4; ++dt) {
            int ch = h * 64 + dt * 16 + lx;        // channel
            size_t base = ((size_t)mtile * 32 + (ch >> 5)) * 512
                        + (size_t)(((ch >> 3) & 3) * 16) * 8 + (ch & 7);
#pragma unroll
            for (int r = 0; r < 4; ++r) {
                float o = acc_o[dt][r] / acc_l[r];
                O[base + (size_t)(quad * 4 + r) * 8] = __float2bfloat16(o);
            }
        }
    };
    auto putC = [&](const f32x4* acc_o, const f32x4& acc_l) {
#pragma unroll
        for (int dt = 0; dt < 4; ++dt)
#pragma unroll
            for (int r = 0; r < 4; ++r)
                cb[(quad * 4 + r) * CS + dt * 16 + lx] = acc_o[dt][r];
        if (lx == 0)
#pragma unroll
            for (int r = 0; r < 4; ++r)
                cb[(quad * 4 + r) * CS + 64] = acc_l[r];
    };
    auto addC = [&](f32x4* acc_o, f32x4& acc_l) {
#pragma unroll
        for (int dt = 0; dt < 4; ++dt)
#pragma unroll
            for (int r = 0; r < 4; ++r)
                acc_o[dt][r] += cb[(quad * 4 + r) * CS + dt * 16 + lx];
#pragma unroll
        for (int r = 0; r < 4; ++r)
            acc_l[r] += cb[(quad * 4 + r) * CS + 64];
    };

    if (half == 1) putC(acc_oH, acc_lH);
    __syncthreads();
    if (half == 0) { addC(acc_oH, acc_lH); writeO(tHi, acc_oH, acc_lH); }
    __syncthreads();
    if (half == 1) putC(acc_oL, acc_lL);
    __syncthreads();
    if (half == 0) { addC(acc_oL, acc_lL); writeO(tLo, acc_oL, acc_lL); }
}

// ---------------------------------------------------------------- launch
extern "C" void kernel_launch(void* const* d_in, const int* in_sizes, int n_in,
                              void* d_out, int out_size, void* d_ws, size_t ws_size,
                              hipStream_t stream)
{
    const float* x  = (const float*)d_in[0];
    const float* Wq = (const float*)d_in[1];
    const float* Wk = (const float*)d_in[2];
    const float* Wv = (const float*)d_in[3];
    const float* Wo = (const float*)d_in[4];
    float* out = (float*)d_out;

    bf16* ws = (bf16*)d_ws;
    bf16* Xf = ws;                    // x fragment-major (aliased by Ab after QKV)
    bf16* Wb = ws + NE;               // Wq,Wk,Wv,Wo bf16 SHUFFLED, contiguous
    bf16* Qb = ws + NE + 4 * WE;      // [B,H,T,D] (pre-scaled by QSCALE)
    bf16* Kb = Qb + NE;               // QK-B-fragment-major per head
    bf16* Vb = Kb + NE;               // PV-B-fragment-major (natural k) per head
    bf16* Ab = Xf;                    // attention out FRAGMENT-MAJOR, reuses Xf

    convert_kernel<<<4096, 256, 0, stream>>>(x, Wq, Wk, Wv, Wo, ws);
    gemm_qkv_kernel<<<dim3(32, 8, 3), 256, 0, stream>>>(Xf, Wb, Qb, Kb, Vb);
    attn_kernel<<<512, 512, 0, stream>>>(Qb, Kb, Vb, Ab);
    gemm_out_kernel<<<dim3(32, 8), 256, 0, stream>>>(Ab, Wb + 3 * WE, out);
}

// Round 8
// 241.432 us; speedup vs baseline: 1.0003x; 1.0003x over previous
//
#include <hip/hip_runtime.h>
#include <hip/hip_bf16.h>

// MultiHeadAttention fused pipeline. FP32 in/out, bf16 MFMA compute, fp32 accum.
// B=2 T=2048 C=1024 H=16 D=64.
// Stage 0: convert x,W* -> bf16 fragment-major (wave frag load = 1KB burst).
// Stage 1: QKV GEMM zero-LDS streaming; RoPE + exp2 scale fused. Q row-major;
//          K QK-B-frag-major; V PV-B-frag-major natural k (8B short4v stores).
// Stage 2: attention, CAUSAL-PAIRED q-tiles + CHUNK-PARITY SPLIT ACROSS
//          BLOCKS: pair (bh,p) -> q-tiles tHi=31-p,tLo=p; two 4-wave blocks
//          per pair (s = chunk parity) each do ~16.5 tile-steps (balanced).
//          1024 blocks x 4 waves at ~85 VGPR (<=128) = 4 waves/SIMD, whole
//          grid co-resident (r7 lesson: 4/SIMD needs <=128 VGPR; the 8-wave
//          dual-tile state spilled). No-max softmax => partials (o,l) are
//          plain sums -> blocks write f32 partials to ws; attn_combine
//          kernel does (O0+O1)/(l0+l1) -> frag-major O. No atomics (graph-
//          safe, deadlock-free). Zero-LDS K/V; P per-wave LDS, stride 68.
// Stage 3: out GEMM zero-LDS streaming 128x128 block / 64x64 wave.
//
// MFMA layouts (HW-verified): A[m=lane&15][k=quad*8+j]; B[n=lane&15][k=quad*8+j];
// C/D: row=quad*4+reg, col=lane&15.

typedef __hip_bfloat16 bf16;
typedef __attribute__((ext_vector_type(8))) short bf16x8;
typedef __attribute__((ext_vector_type(4))) float f32x4;
typedef __attribute__((ext_vector_type(4))) short short4v;

#define MFMA16(a, b, c) __builtin_amdgcn_mfma_f32_16x16x32_bf16((a), (b), (c), 0, 0, 0)

constexpr int Bn = 2, Hn = 16, Tn = 2048, Dn = 64, Cn = 1024;
constexpr size_t NE = (size_t)Bn * Tn * Cn;   // 4,194,304
constexpr size_t WE = (size_t)Cn * Cn;        // 1,048,576
constexpr float QSCALE = 0.125f * 1.44269504088896f;   // 1/8 * log2(e)
constexpr int PS = 68;   // P-buffer row stride in shorts (2-way banks = free)

__device__ inline unsigned short bfbits(float x) {
    bf16 b = __float2bfloat16(x);
    return *(unsigned short*)&b;
}

__device__ inline bf16x8 pack8(f32x4 a, f32x4 b) {
    bf16x8 r;
#pragma unroll
    for (int i = 0; i < 4; ++i) r[i] = (short)bfbits(a[i]);
#pragma unroll
    for (int i = 0; i < 4; ++i) r[4 + i] = (short)bfbits(b[i]);
    return r;
}

// ---------------------------------------------------------------- convert
// blocks [0,2048): x -> fragment-major. [2048,4096): W* -> fragment-major.
__global__ __launch_bounds__(256) void convert_kernel(
    const float* __restrict__ x, const float* __restrict__ wq,
    const float* __restrict__ wk, const float* __restrict__ wv,
    const float* __restrict__ wo, bf16* __restrict__ dst)
{
    int blk = blockIdx.x;
    int lane = threadIdx.x & 63;
    int lx = lane & 15, quad = lane >> 4;
    const float* src;
    size_t doff;
    if (blk < 2048) {
        int frag = blk * 4 + (threadIdx.x >> 6);   // 0..8191
        int mt = frag >> 5, kc = frag & 31;
        src = x + (size_t)(mt * 16 + lx) * Cn + kc * 32 + quad * 8;
        doff = (size_t)frag * 512 + lane * 8;
    } else {
        int w = (blk - 2048) >> 9, b = (blk - 2048) & 511;
        const float* s4[4] = {wq, wk, wv, wo};
        int frag = b * 4 + (threadIdx.x >> 6);     // 0..2047
        int nb = frag >> 5, kc = frag & 31;
        src = s4[w] + (size_t)(nb * 16 + lx) * Cn + kc * 32 + quad * 8;
        doff = NE + (size_t)w * WE + (size_t)frag * 512 + lane * 8;
    }
    f32x4 a = *(const f32x4*)(src);
    f32x4 b2 = *(const f32x4*)(src + 4);
    *(bf16x8*)(dst + doff) = pack8(a, b2);
}

// ---------------------------------------------------------------- QKV GEMM
// ZERO-LDS streaming GEMM (round-0 proven): 4 waves (2x2), wave 64x64,
// K-step 32, cur/next prefetch, no barriers. Epilogue: Q row-major;
// K frag-major; V natural-frag (8B short4v stores).
__global__ __launch_bounds__(256) void gemm_qkv_kernel(
    const bf16* __restrict__ Xf, const bf16* __restrict__ Wbase,
    bf16* __restrict__ Qo, bf16* __restrict__ Ko, bf16* __restrict__ Vo)
{
    const int bm = blockIdx.x, bn = blockIdx.y, wsel = blockIdx.z;
    const bf16* W = Wbase + (size_t)wsel * WE;
    const int tid  = threadIdx.x;
    const int wave = tid >> 6, lane = tid & 63;
    const int lx   = lane & 15, quad = lane >> 4;
    const int wm = wave >> 1, wn = wave & 1;

    const int mt0 = bm * 8 + wm * 4;
    const int nb0 = bn * 8 + wn * 4;
    const bf16* afrag = Xf + (size_t)mt0 * 32 * 512 + (size_t)lane * 8;
    const bf16* wfrag = W + (size_t)nb0 * 32 * 512 + (size_t)lane * 8;

    f32x4 acc[4][4] = {};   // [mt][nt]
    bf16x8 acur[4], bcur[4], anxt[4], bnxt[4];
#pragma unroll
    for (int i = 0; i < 4; ++i) {
        acur[i] = *(const bf16x8*)(afrag + (size_t)i * 32 * 512);
        bcur[i] = *(const bf16x8*)(wfrag + (size_t)i * 32 * 512);
    }
    for (int kc = 0; kc < 32; ++kc) {
        if (kc < 31) {
#pragma unroll
            for (int i = 0; i < 4; ++i) {
                anxt[i] = *(const bf16x8*)(afrag + ((size_t)i * 32 + kc + 1) * 512);
                bnxt[i] = *(const bf16x8*)(wfrag + ((size_t)i * 32 + kc + 1) * 512);
            }
        }
#pragma unroll
        for (int mt = 0; mt < 4; ++mt)
#pragma unroll
            for (int nt = 0; nt < 4; ++nt)
                acc[mt][nt] = MFMA16(acur[mt], bcur[nt], acc[mt][nt]);
#pragma unroll
        for (int i = 0; i < 4; ++i) { acur[i] = anxt[i]; bcur[i] = bnxt[i]; }
    }

    const int h = bn * 2 + wn;   // 64-col wave block == one head
    if (wsel <= 1) {             // fused RoPE: pair (d, d+32) = (nt, nt+2)
#pragma unroll
        for (int mt = 0; mt < 4; ++mt)
#pragma unroll
            for (int r = 0; r < 4; ++r) {
                int mg = bm * 128 + wm * 64 + mt * 16 + quad * 4 + r;
                int t  = mg & (Tn - 1);
#pragma unroll
                for (int nt = 0; nt < 2; ++nt) {
                    int d = nt * 16 + lx;   // 0..31
                    float ang = (float)t * __expf(-(float)d * 0.2878231366f);
                    float c, s;
                    __sincosf(ang, &s, &c);
                    float a0 = acc[mt][nt][r], a1 = acc[mt][nt + 2][r];
                    acc[mt][nt][r]     = a0 * c - a1 * s;
                    acc[mt][nt + 2][r] = a1 * c + a0 * s;
                }
            }
    }

#pragma unroll
    for (int mt = 0; mt < 4; ++mt) {
        int mg0 = bm * 128 + wm * 64 + mt * 16 + quad * 4;
        int b = mg0 >> 11, tlo = mg0 & (Tn - 1);
        if (wsel == 0) {        // Q: row-major [B,H,T,D], exp2-folded scale
#pragma unroll
            for (int nt = 0; nt < 4; ++nt)
#pragma unroll
                for (int r = 0; r < 4; ++r) {
                    int d = nt * 16 + lx;
                    Qo[((size_t)(b * Hn + h) * Tn + tlo + r) * Dn + d] =
                        __float2bfloat16(acc[mt][nt][r] * QSCALE);
                }
        } else if (wsel == 1) { // K: QK-B-fragment-major per head
            bf16* Kf = Ko + (size_t)(b * Hn + h) * Tn * Dn;
            int c = tlo >> 6, ntk = (tlo >> 4) & 3;
#pragma unroll
            for (int nt = 0; nt < 4; ++nt) {
                size_t base = ((size_t)(c * 4 + ntk) * 2 + (nt >> 1)) * 512
                            + (size_t)((nt & 1) * 2 + (lx >> 3)) * 128
                            + (size_t)(tlo & 15) * 8 + (lx & 7);
#pragma unroll
                for (int r = 0; r < 4; ++r)
                    Kf[base + (size_t)r * 8] = __float2bfloat16(acc[mt][nt][r]);
            }
        } else {                // V: natural-k frag-major, 8B stores (r13)
            bf16* Vf = Vo + (size_t)(b * Hn + h) * Tn * Dn;
            int c = tlo >> 6, ksv = (tlo >> 5) & 1;
            int qv = (tlo >> 3) & 3, pos0 = tlo & 7;
#pragma unroll
            for (int nt = 0; nt < 4; ++nt) {
                short4v pk;
#pragma unroll
                for (int r = 0; r < 4; ++r) pk[r] = (short)bfbits(acc[mt][nt][r]);
                *(short4v*)&Vf[((size_t)(c * 8 + nt * 2 + ksv)) * 512
                               + (size_t)qv * 128 + (size_t)lx * 8 + pos0] = pk;
            }
        }
    }
}

// ---------------------------------------------------------------- out GEMM
// ZERO-LDS streaming, 128x128 block / 64x64 wave. Grid (32, 8).
__global__ __launch_bounds__(256) void gemm_out_kernel(
    const bf16* __restrict__ Af, const bf16* __restrict__ W, float* __restrict__ Out)
{
    const int bm = blockIdx.x, bn = blockIdx.y;
    const int tid  = threadIdx.x;
    const int wave = tid >> 6, lane = tid & 63;
    const int lx   = lane & 15, quad = lane >> 4;
    const int wm = wave >> 1, wn = wave & 1;

    const int mt0 = bm * 8 + wm * 4;
    const int nb0 = bn * 8 + wn * 4;
    const bf16* afrag = Af + (size_t)mt0 * 32 * 512 + (size_t)lane * 8;
    const bf16* wfrag = W + (size_t)nb0 * 32 * 512 + (size_t)lane * 8;

    f32x4 acc[4][4] = {};
    bf16x8 acur[4], bcur[4], anxt[4], bnxt[4];
#pragma unroll
    for (int i = 0; i < 4; ++i) {
        acur[i] = *(const bf16x8*)(afrag + (size_t)i * 32 * 512);
        bcur[i] = *(const bf16x8*)(wfrag + (size_t)i * 32 * 512);
    }
    for (int kc = 0; kc < 32; ++kc) {
        if (kc < 31) {
#pragma unroll
            for (int i = 0; i < 4; ++i) {
                anxt[i] = *(const bf16x8*)(afrag + ((size_t)i * 32 + kc + 1) * 512);
                bnxt[i] = *(const bf16x8*)(wfrag + ((size_t)i * 32 + kc + 1) * 512);
            }
        }
#pragma unroll
        for (int mt = 0; mt < 4; ++mt)
#pragma unroll
            for (int nt = 0; nt < 4; ++nt)
                acc[mt][nt] = MFMA16(acur[mt], bcur[nt], acc[mt][nt]);
#pragma unroll
        for (int i = 0; i < 4; ++i) { acur[i] = anxt[i]; bcur[i] = bnxt[i]; }
    }
#pragma unroll
    for (int mt = 0; mt < 4; ++mt)
#pragma unroll
        for (int nt = 0; nt < 4; ++nt)
#pragma unroll
            for (int r = 0; r < 4; ++r) {
                int mg = bm * 128 + wm * 64 + mt * 16 + quad * 4 + r;
                int ng = bn * 128 + wn * 64 + nt * 16 + lx;
                Out[(size_t)mg * Cn + ng] = acc[mt][nt][r];
            }
}

// ---------------------------------------------------------------- Attention
// 1024 blocks x 4 waves: g -> bh = g&31, p = (g>>5)&15, s = g>>9 (parity).
// Block handles q-tiles tHi=31-p, tLo=p over chunks c = s, s+2, ... <= tHi
// (hi step always, lo step while c<=tLo). One K/V register load per chunk
// feeds both tile-steps. ~16.5 tile-steps/block, uniform. Partials (o,l)
// written f32 to ws; combine kernel finishes. Zero-LDS K/V; P per-wave LDS.
__global__ __launch_bounds__(256, 4) void attn_kernel(
    const bf16* __restrict__ Q, const bf16* __restrict__ K,
    const bf16* __restrict__ Vt, float* __restrict__ Opart,
    float* __restrict__ lpart)
{
    __shared__ unsigned short Pl[4][16 * PS];
    const int g  = blockIdx.x;
    const int bh = g & 31;
    const int p  = (g >> 5) & 15;       // 0..15
    const int s  = g >> 9;              // chunk parity 0/1
    const int tHi = 31 - p, tLo = p;    // tHi >= 16 > 15 >= tLo
    const int tid  = threadIdx.x;
    const int wave = tid >> 6, lane = tid & 63;
    const int lx   = lane & 15, quad = lane >> 4;

    const bf16* Qh = Q  + (size_t)bh * Tn * Dn;
    const bf16* Kh = K  + (size_t)bh * Tn * Dn;   // frag-major, 4096 shorts/chunk
    const bf16* Vh = Vt + (size_t)bh * Tn * Dn;   // natural-k frag-major
    unsigned short* pw = &Pl[wave][0];

    const int qrowH = tHi * 64 + wave * 16 + lx;  // A-frag m index (hi tile)
    bf16x8 aqH0 = *(const bf16x8*)(Qh + (size_t)qrowH * Dn + quad * 8);
    bf16x8 aqH1 = *(const bf16x8*)(Qh + (size_t)qrowH * Dn + 32 + quad * 8);
    const int qrowL = tLo * 64 + wave * 16 + lx;  // (lo tile)
    bf16x8 aqL0 = *(const bf16x8*)(Qh + (size_t)qrowL * Dn + quad * 8);
    bf16x8 aqL1 = *(const bf16x8*)(Qh + (size_t)qrowL * Dn + 32 + quad * 8);

    bf16x8 ones;
#pragma unroll
    for (int i = 0; i < 8; ++i) ones[i] = (short)0x3F80;

    f32x4 acc_oH[4] = {}, acc_oL[4] = {};
    f32x4 acc_lH = {},    acc_lL = {};
    const int row_local = wave * 16 + quad * 4;

    // softmax -> per-wave P buffer (slot = key, natural order)
    auto storeP = [&](const f32x4* accs, bool diag) {
        if (!diag) {
#pragma unroll
            for (int nt = 0; nt < 4; ++nt)
#pragma unroll
                for (int r = 0; r < 4; ++r)
                    pw[(quad * 4 + r) * PS + nt * 16 + lx] = bfbits(exp2f(accs[nt][r]));
        } else {
#pragma unroll
            for (int nt = 0; nt < 4; ++nt) {
                int keyl = nt * 16 + lx;
#pragma unroll
                for (int r = 0; r < 4; ++r) {
                    float pv = (keyl > row_local + r) ? 0.0f : exp2f(accs[nt][r]);
                    pw[(quad * 4 + r) * PS + nt * 16 + lx] = bfbits(pv);
                }
            }
        }
    };

    for (int c = s; c <= tHi; c += 2) {
        // K/V chunk load (registers; L2-resident frag-major layout)
        const bf16* kp = Kh + (size_t)c * 4096 + lane * 8;
        const bf16* vp = Vh + (size_t)c * 4096 + lane * 8;
        bf16x8 k[8], v[8];
#pragma unroll
        for (int i = 0; i < 8; ++i) {
            k[i] = *(const bf16x8*)(kp + (size_t)i * 512);
            v[i] = *(const bf16x8*)(vp + (size_t)i * 512);
        }
        const bool lo = (c <= tLo);
        // QK for both tiles first (independent MFMAs; scheduler freedom)
        f32x4 accsH[4] = {};
#pragma unroll
        for (int nt = 0; nt < 4; ++nt) {
            accsH[nt] = MFMA16(aqH0, k[nt * 2], accsH[nt]);
            accsH[nt] = MFMA16(aqH1, k[nt * 2 + 1], accsH[nt]);
        }
        f32x4 accsL[4] = {};
        if (lo) {
#pragma unroll
            for (int nt = 0; nt < 4; ++nt) {
                accsL[nt] = MFMA16(aqL0, k[nt * 2], accsL[nt]);
                accsL[nt] = MFMA16(aqL1, k[nt * 2 + 1], accsL[nt]);
            }
        }
        // ---- hi tile: softmax -> P -> l,PV
        storeP(accsH, c == tHi);
        asm volatile("s_waitcnt lgkmcnt(0)" ::: "memory");
        {
            bf16x8 ap0 = *(const bf16x8*)&pw[lx * PS + quad * 8];
            bf16x8 ap1 = *(const bf16x8*)&pw[lx * PS + 32 + quad * 8];
            acc_lH = MFMA16(ap0, ones, acc_lH);
            acc_lH = MFMA16(ap1, ones, acc_lH);
#pragma unroll
            for (int dt = 0; dt < 4; ++dt) {
                acc_oH[dt] = MFMA16(ap0, v[dt * 2], acc_oH[dt]);
                acc_oH[dt] = MFMA16(ap1, v[dt * 2 + 1], acc_oH[dt]);
            }
        }
        // ---- lo tile: same P buffer reused (same-wave DS ops are in-order)
        if (lo) {
            storeP(accsL, c == tLo);
            asm volatile("s_waitcnt lgkmcnt(0)" ::: "memory");
            bf16x8 ap0 = *(const bf16x8*)&pw[lx * PS + quad * 8];
            bf16x8 ap1 = *(const bf16x8*)&pw[lx * PS + 32 + quad * 8];
            acc_lL = MFMA16(ap0, ones, acc_lL);
            acc_lL = MFMA16(ap1, ones, acc_lL);
#pragma unroll
            for (int dt = 0; dt < 4; ++dt) {
                acc_oL[dt] = MFMA16(ap0, v[dt * 2], acc_oL[dt]);
                acc_oL[dt] = MFMA16(ap1, v[dt * 2 + 1], acc_oL[dt]);
            }
        }
    }

    // ---- partial store: [pair][parity][row 0..127][ch 0..63] f32 (+ l)
    const int pairIdx = g & 511;
    float* Op = Opart + ((size_t)pairIdx * 2 + s) * 8192;
    float* lp = lpart + ((size_t)pairIdx * 2 + s) * 128;
    auto storePart = [&](int roff, const f32x4* acc_o, const f32x4& acc_l) {
#pragma unroll
        for (int dt = 0; dt < 4; ++dt)
#pragma unroll
            for (int r = 0; r < 4; ++r)
                Op[(size_t)(roff + wave * 16 + quad * 4 + r) * 64 + dt * 16 + lx]
                    = acc_o[dt][r];
        if (lx == 0)
#pragma unroll
            for (int r = 0; r < 4; ++r)
                lp[roff + wave * 16 + quad * 4 + r] = acc_l[r];
    };
    storePart(0, acc_oH, acc_lH);    // hi rows [0,64)
    storePart(64, acc_oL, acc_lL);   // lo rows [64,128)
}

// ---------------------------------------------------------------- combine
// 512 blocks, one pair each: O = (O0+O1)/(l0+l1), write frag-major bf16.
__global__ __launch_bounds__(256) void attn_combine_kernel(
    const float* __restrict__ Opart, const float* __restrict__ lpart,
    bf16* __restrict__ O)
{
    const int pair = blockIdx.x;        // (bh, p)
    const int bh = pair & 31, p = pair >> 5;
    const int tHi = 31 - p, tLo = p;
    const int b = bh >> 4, h = bh & 15;
    const float* O0 = Opart + (size_t)pair * 2 * 8192;
    const float* O1 = O0 + 8192;
    const float* l0 = lpart + (size_t)pair * 2 * 128;
    const float* l1 = l0 + 128;
    for (int idx = threadIdx.x; idx < 8192; idx += 256) {
        int row = idx >> 6, ch = idx & 63;
        float l = l0[row] + l1[row];
        float o = (O0[idx] + O1[idx]) / l;
        int t  = (row < 64) ? tHi : tLo;
        int rl = row & 63;
        int mtile = b * 128 + t * 4 + (rl >> 4);
        int chg = h * 64 + ch;
        size_t base = ((size_t)mtile * 32 + (chg >> 5)) * 512
                    + (size_t)(((chg >> 3) & 3) * 16) * 8 + (chg & 7);
        O[base + (size_t)(rl & 15) * 8] = __float2bfloat16(o);
    }
}

// ---------------------------------------------------------------- launch
extern "C" void kernel_launch(void* const* d_in, const int* in_sizes, int n_in,
                              void* d_out, int out_size, void* d_ws, size_t ws_size,
                              hipStream_t stream)
{
    const float* x  = (const float*)d_in[0];
    const float* Wq = (const float*)d_in[1];
    const float* Wk = (const float*)d_in[2];
    const float* Wv = (const float*)d_in[3];
    const float* Wo = (const float*)d_in[4];
    float* out = (float*)d_out;

    bf16* ws = (bf16*)d_ws;
    bf16* Xf = ws;                    // x fragment-major (aliased by Ab after QKV)
    bf16* Wb = ws + NE;               // Wq,Wk,Wv,Wo bf16 SHUFFLED, contiguous
    bf16* Qb = ws + NE + 4 * WE;      // [B,H,T,D] (pre-scaled by QSCALE)
    bf16* Kb = Qb + NE;               // QK-B-fragment-major per head
    bf16* Vb = Kb + NE;               // PV-B-fragment-major (natural k) per head
    bf16* Ab = Xf;                    // attention out FRAGMENT-MAJOR, reuses Xf
    // f32 partials after the bf16 region (40 MB): 32 MB O + 0.5 MB l
    float* Opart = (float*)(ws + 4 * NE + 4 * WE);
    float* lpart = Opart + (size_t)512 * 2 * 8192;

    convert_kernel<<<4096, 256, 0, stream>>>(x, Wq, Wk, Wv, Wo, ws);
    gemm_qkv_kernel<<<dim3(32, 8, 3), 256, 0, stream>>>(Xf, Wb, Qb, Kb, Vb);
    attn_kernel<<<1024, 256, 0, stream>>>(Qb, Kb, Vb, Opart, lpart);
    attn_combine_kernel<<<512, 256, 0, stream>>>(Opart, lpart, Ab);
    gemm_out_kernel<<<dim3(32, 8), 256, 0, stream>>>(Ab, Wb + 3 * WE, out);
}